// Round 5
// baseline (947.583 us; speedup 1.0000x reference)
//
#include <hip/hip_runtime.h>
#include <hip/hip_bf16.h>
#include <math.h>

#define NN 32768      // B*NPG nodes
#define BG 64         // graphs
#define NPGC 512      // nodes per graph
#define DD 128        // hidden dim
#define EE 524288     // edges
#define LL 10         // layers
#define EPSF 1e-5f
#define ECAP 128      // staged edges per wave per chunk

// XCD-aware block->work swizzle: presumed round-robin blockIdx%8 -> XCD.
// Confirmed R4: k_agg FETCH_SIZE 113MB -> 10.7MB. All per-graph work maps to
// blocks with blockIdx%8 == g%8 so each graph's 256KB slice stays in one XCD L2.

// ---------------- prologue: degrees, CSR build ----------------
__global__ void k_hist(const int* __restrict__ dst, int* __restrict__ cnt) {
    int e = blockIdx.x * 256 + threadIdx.x;
    atomicAdd(&cnt[dst[e]], 1);
}

__global__ void k_dinv(const int* __restrict__ cnt, float* __restrict__ dinv) {
    int n = blockIdx.x * 256 + threadIdx.x;
    dinv[n] = rsqrtf(1.0f + (float)cnt[n]);
}

// exclusive scan of cnt[NN] -> rp[NN+1], single block of 1024, 32 elems/thread
__global__ void k_scan(const int* __restrict__ cnt, int* __restrict__ rp) {
    __shared__ int s[1024];
    int t = threadIdx.x;
    int loc[32];
    int base = t * 32, tot = 0;
    for (int i = 0; i < 32; i++) { loc[i] = cnt[base + i]; tot += loc[i]; }
    s[t] = tot;
    __syncthreads();
    for (int off = 1; off < 1024; off <<= 1) {
        int add = (t >= off) ? s[t - off] : 0;
        __syncthreads();
        s[t] += add;
        __syncthreads();
    }
    int ex = (t == 0) ? 0 : s[t - 1];
    for (int i = 0; i < 32; i++) { rp[base + i] = ex; ex += loc[i]; }
    if (t == 1023) rp[NN] = ex;   // == EE
}

__global__ void k_fill(const int* __restrict__ src, const int* __restrict__ dst,
                       const float* __restrict__ dinv, const int* __restrict__ rp,
                       int* __restrict__ cursor, int* __restrict__ csr_src,
                       float* __restrict__ csr_w) {
    int e = blockIdx.x * 256 + threadIdx.x;
    int d = dst[e], sx = src[e];
    int p = atomicAdd(&cursor[d], 1);
    int i = rp[d] + p;
    csr_src[i] = sx;
    csr_w[i] = dinv[sx] * dinv[d];
}

// layer-0 "matmul": D_IN=1 outer product, hw = x * W0 row (fp32)
__global__ void k_l0(const float* __restrict__ x, const float* __restrict__ W0,
                     float* __restrict__ hw) {
    int idx = blockIdx.x * 256 + threadIdx.x;
    hw[idx] = x[idx >> 7] * W0[idx & 127];
}

#define FMA4(A, W, V) do { (A).x = fmaf((W), (V).x, (A).x); \
                           (A).y = fmaf((W), (V).y, (A).y); \
                           (A).z = fmaf((W), (V).z, (A).z); \
                           (A).w = fmaf((W), (V).w, (A).w); } while (0)

// ---------------- per-layer: aggregate (gather) + BN stats ----------------
// 2048 blocks, 16 nodes/block, 4 nodes/wave. Quarter-wave slots (el=lane>>4)
// each cover the full 128-feature row as 16 lanes x 2 float4. Edge indices/
// weights staged to LDS first (coalesced, chunked with uniform trip count),
// so gathers issue back-to-back with ~8 loads in flight per wave instead of
// serializing behind the per-edge index load. Slots combined via shfl_xor.
__global__ __launch_bounds__(256) void k_agg(const float* __restrict__ hw,
        const float* __restrict__ dinv, const int* __restrict__ rp,
        const int* __restrict__ csr_src, const float* __restrict__ csr_w,
        const float* __restrict__ bias, float* __restrict__ pre,
        float* __restrict__ stats) {
    __shared__ int   s_idx[4][ECAP];
    __shared__ float s_w[4][ECAP];
    __shared__ float ssum[512], ssq[512];   // [wave][128]
    __shared__ int s_nch[4];
    int t = threadIdx.x, lane = t & 63, wv = t >> 6;
    int el = lane >> 4;          // slot 0..3
    int fl = (lane & 15) * 8;    // feature base: 8 floats per lane
    int b = blockIdx.x, r = b & 7, q = b >> 3;      // q: 0..255
    int g = r + 8 * (q & 7);                        // graph 0..63
    int nb = g * NPGC + (q >> 3) * 16;              // 32 chunks of 16 nodes
    int nw0 = nb + wv * 4;

    int rpl[5];
    #pragma unroll
    for (int i = 0; i < 5; i++) rpl[i] = rp[nw0 + i];
    int web = rpl[0], wee = rpl[4];

    if (lane == 0) s_nch[wv] = (wee - web + ECAP - 1) / ECAP;
    __syncthreads();
    int mx = max(max(s_nch[0], s_nch[1]), max(s_nch[2], s_nch[3]));

    float4 accA[4], accB[4];
    #pragma unroll
    for (int i = 0; i < 4; i++) {
        accA[i] = make_float4(0.f, 0.f, 0.f, 0.f);
        accB[i] = make_float4(0.f, 0.f, 0.f, 0.f);
    }

    for (int c = 0; c < mx; c++) {
        int base = web + c * ECAP;
        int m = min(ECAP, wee - base);   // may be <=0 for finished waves
        __syncthreads();                 // protect previous chunk's reads
        for (int j = lane; j < m; j += 64) {
            s_idx[wv][j] = csr_src[base + j];
            s_w[wv][j]   = csr_w[base + j];
        }
        __syncthreads();
        #pragma unroll
        for (int i = 0; i < 4; i++) {
            int lo = max(rpl[i], base), hi = min(rpl[i + 1], base + m);
            int e = lo + el;
            // batch-2: 4 float4 gathers in flight per slot
            for (; e + 4 < hi; e += 8) {
                int j0 = e - base, j1 = j0 + 4;
                int sx0 = s_idx[wv][j0]; float w0 = s_w[wv][j0];
                int sx1 = s_idx[wv][j1]; float w1 = s_w[wv][j1];
                const float4* p0 = (const float4*)(hw + (size_t)sx0 * 128 + fl);
                const float4* p1 = (const float4*)(hw + (size_t)sx1 * 128 + fl);
                float4 va = p0[0], vb = p0[1], vc = p1[0], vd = p1[1];
                FMA4(accA[i], w0, va); FMA4(accB[i], w0, vb);
                FMA4(accA[i], w1, vc); FMA4(accB[i], w1, vd);
            }
            for (; e < hi; e += 4) {
                int j0 = e - base;
                int sx0 = s_idx[wv][j0]; float w0 = s_w[wv][j0];
                const float4* p0 = (const float4*)(hw + (size_t)sx0 * 128 + fl);
                float4 va = p0[0], vb = p0[1];
                FMA4(accA[i], w0, va); FMA4(accB[i], w0, vb);
            }
        }
    }

    // combine 4 slots, then el==0 finishes: self-loop + bias + store + stats
    float4 b4a = *(const float4*)(bias + fl);
    float4 b4b = *(const float4*)(bias + fl + 4);
    float4 lsA = make_float4(0.f, 0.f, 0.f, 0.f), lsB = lsA;
    float4 lqA = lsA, lqB = lsA;
    #pragma unroll
    for (int i = 0; i < 4; i++) {
        float4 A = accA[i], B = accB[i];
        #pragma unroll
        for (int off = 16; off <= 32; off <<= 1) {
            A.x += __shfl_xor(A.x, off); A.y += __shfl_xor(A.y, off);
            A.z += __shfl_xor(A.z, off); A.w += __shfl_xor(A.w, off);
            B.x += __shfl_xor(B.x, off); B.y += __shfl_xor(B.y, off);
            B.z += __shfl_xor(B.z, off); B.w += __shfl_xor(B.w, off);
        }
        if (el == 0) {
            int n = nw0 + i;
            float dv = dinv[n], s = dv * dv;
            const float4* hp = (const float4*)(hw + (size_t)n * 128 + fl);
            float4 ha = hp[0], hb = hp[1];
            A.x = fmaf(s, ha.x, A.x + b4a.x); A.y = fmaf(s, ha.y, A.y + b4a.y);
            A.z = fmaf(s, ha.z, A.z + b4a.z); A.w = fmaf(s, ha.w, A.w + b4a.w);
            B.x = fmaf(s, hb.x, B.x + b4b.x); B.y = fmaf(s, hb.y, B.y + b4b.y);
            B.z = fmaf(s, hb.z, B.z + b4b.z); B.w = fmaf(s, hb.w, B.w + b4b.w);
            float4* pp = (float4*)(pre + (size_t)n * 128 + fl);
            pp[0] = A; pp[1] = B;
            lsA.x += A.x; lsA.y += A.y; lsA.z += A.z; lsA.w += A.w;
            lsB.x += B.x; lsB.y += B.y; lsB.z += B.z; lsB.w += B.w;
            lqA.x = fmaf(A.x, A.x, lqA.x); lqA.y = fmaf(A.y, A.y, lqA.y);
            lqA.z = fmaf(A.z, A.z, lqA.z); lqA.w = fmaf(A.w, A.w, lqA.w);
            lqB.x = fmaf(B.x, B.x, lqB.x); lqB.y = fmaf(B.y, B.y, lqB.y);
            lqB.z = fmaf(B.z, B.z, lqB.z); lqB.w = fmaf(B.w, B.w, lqB.w);
        }
    }
    if (el == 0) {
        *(float4*)(&ssum[wv * 128 + fl]) = lsA;
        *(float4*)(&ssum[wv * 128 + fl + 4]) = lsB;
        *(float4*)(&ssq[wv * 128 + fl]) = lqA;
        *(float4*)(&ssq[wv * 128 + fl + 4]) = lqB;
    }
    __syncthreads();
    if (t < 128) {
        float a = ssum[t] + ssum[128 + t] + ssum[256 + t] + ssum[384 + t];
        float qq = ssq[t] + ssq[128 + t] + ssq[256 + t] + ssq[384 + t];
        atomicAdd(&stats[t], a);
        atomicAdd(&stats[128 + t], qq);
    }
}

// ---------------- fused BN+ReLU+matmul: hw_next = relu(bn(pre)) @ W --------
// 64x128 tile, 512 blocks (2/CU), 256 threads, 4x8 microtile, BK=64, 48KB LDS.
// BN affine computed inline from stats. XCD-swizzled.
__global__ __launch_bounds__(256) void k_mm(const float* __restrict__ pre,
        const float* __restrict__ stats, const float* __restrict__ gamma,
        const float* __restrict__ beta, const float* __restrict__ W,
        float* __restrict__ hw) {
    __shared__ float Hst[64 * 64];   // [kloc][n]  16KB
    __shared__ float Ws[64 * 128];   // [kloc][f]  32KB
    __shared__ float scL[256];
    int t = threadIdx.x;
    int b = blockIdx.x, r = b & 7, q = b >> 3;      // q: 0..63
    int g = r + 8 * (q & 7);
    int nb = g * NPGC + (q >> 3) * 64;              // 8 chunks of 64 nodes
    if (t < 128) {
        float mu = stats[t] * (1.0f / NN);
        float var = stats[128 + t] * (1.0f / NN) - mu * mu;
        float s = gamma[t] * rsqrtf(var + EPSF);
        scL[t] = s;
        scL[128 + t] = fmaf(-mu, s, beta[t]);
    }
    int rq = t >> 4, cq = t & 15;
    int r0 = rq * 4, c0 = cq * 8;
    float acc[4][8];
    #pragma unroll
    for (int i = 0; i < 4; i++)
        #pragma unroll
        for (int j = 0; j < 8; j++) acc[i][j] = 0.f;

    for (int kk = 0; kk < 128; kk += 64) {
        __syncthreads();   // also publishes scL on first iteration
        for (int i = 0; i < 4; i++) {
            int idx = t + i * 256;            // 1024 float4 slots
            int row = idx & 63;
            int kc = (idx >> 6) * 4;          // 0..60
            float4 v  = *(const float4*)(pre + (nb + row) * 128 + kk + kc);
            float4 s4 = *(const float4*)(&scL[kk + kc]);
            float4 h4 = *(const float4*)(&scL[128 + kk + kc]);
            Hst[(kc + 0) * 64 + row] = fmaxf(fmaf(v.x, s4.x, h4.x), 0.f);
            Hst[(kc + 1) * 64 + row] = fmaxf(fmaf(v.y, s4.y, h4.y), 0.f);
            Hst[(kc + 2) * 64 + row] = fmaxf(fmaf(v.z, s4.z, h4.z), 0.f);
            Hst[(kc + 3) * 64 + row] = fmaxf(fmaf(v.w, s4.w, h4.w), 0.f);
        }
        for (int i = 0; i < 8; i++) {
            int idx = t + i * 256;            // 2048 float4 slots
            *(float4*)(&Ws[idx * 4]) = *(const float4*)(W + kk * 128 + idx * 4);
        }
        __syncthreads();
        for (int k = 0; k < 64; k++) {
            float4 a4 = *(const float4*)&Hst[k * 64 + r0];
            float4 b0 = *(const float4*)&Ws[k * 128 + c0];
            float4 b1 = *(const float4*)&Ws[k * 128 + c0 + 4];
            float a[4] = {a4.x, a4.y, a4.z, a4.w};
            float bb[8] = {b0.x, b0.y, b0.z, b0.w, b1.x, b1.y, b1.z, b1.w};
            #pragma unroll
            for (int ii = 0; ii < 4; ii++)
                #pragma unroll
                for (int jj = 0; jj < 8; jj++)
                    acc[ii][jj] = fmaf(a[ii], bb[jj], acc[ii][jj]);
        }
    }
    for (int ii = 0; ii < 4; ii++) {
        int n = nb + r0 + ii;
        float4 o0 = make_float4(acc[ii][0], acc[ii][1], acc[ii][2], acc[ii][3]);
        float4 o1 = make_float4(acc[ii][4], acc[ii][5], acc[ii][6], acc[ii][7]);
        *(float4*)(hw + n * 128 + c0) = o0;
        *(float4*)(hw + n * 128 + c0 + 4) = o1;
    }
}

// last layer: BN+ReLU in-place + per-graph column sums. 512 blocks, swizzled.
__global__ __launch_bounds__(256) void k_bn_pool(float* __restrict__ pre,
        const float* __restrict__ stats, const float* __restrict__ gamma,
        const float* __restrict__ beta, float* __restrict__ meansum) {
    __shared__ float ssum[256];
    __shared__ float scL[256];
    int t = threadIdx.x;
    int b = blockIdx.x, r = b & 7, q = b >> 3;
    int g = r + 8 * (q & 7);
    int nb = g * NPGC + (q >> 3) * 64;
    if (t < 128) {
        float mu = stats[t] * (1.0f / NN);
        float var = stats[128 + t] * (1.0f / NN) - mu * mu;
        float s = gamma[t] * rsqrtf(var + EPSF);
        scL[t] = s;
        scL[128 + t] = fmaf(-mu, s, beta[t]);
    }
    __syncthreads();
    int f = t & 127;
    float s = scL[f], sh = scL[128 + f];
    float lsum = 0.f;
    int base = nb * 128;
    for (int i = 0; i < 32; i++) {
        int idx = base + i * 256 + t;
        float v = fmaxf(fmaf(pre[idx], s, sh), 0.f);
        pre[idx] = v;
        lsum += v;
    }
    ssum[t] = lsum;
    __syncthreads();
    if (t < 128) atomicAdd(&meansum[g * 128 + f], ssum[t] + ssum[t + 128]);
}

// tg = tanh((meansum/512) @ W_att), per graph
__global__ void k_tg(const float* __restrict__ meansum, const float* __restrict__ Watt,
                     float* __restrict__ tg) {
    __shared__ float m[128];
    int g = blockIdx.x, t = threadIdx.x;  // 128 threads
    m[t] = meansum[g * 128 + t] * (1.0f / NPGC);
    __syncthreads();
    float a2 = 0.f;
    for (int k = 0; k < 128; k++) a2 = fmaf(m[k], Watt[k * 128 + t], a2);
    tg[g * 128 + t] = tanhf(a2);
}

// coefs = sigmoid(10*<h,tg>) and gf += coef*h. 512 blocks, 64 nodes each, swizzled.
__global__ __launch_bounds__(256) void k_coef_gf(const float* __restrict__ h,
        const float* __restrict__ tg, float* __restrict__ gf) {
    __shared__ float tgs[128];
    __shared__ float coef[64];
    int t = threadIdx.x;
    int b = blockIdx.x, r = b & 7, q = b >> 3;
    int g = r + 8 * (q & 7);
    int n0 = (q >> 3) * 64;                   // local node base within graph
    if (t < 128) tgs[t] = tg[g * 128 + t];
    __syncthreads();
    int wid = t >> 6, lane = t & 63;
    const float* hp = h + (size_t)g * NPGC * 128;
    for (int j = wid; j < 64; j += 4) {
        int n = n0 + j;
        float p = hp[n * 128 + lane] * tgs[lane] + hp[n * 128 + 64 + lane] * tgs[64 + lane];
        for (int off = 32; off; off >>= 1) p += __shfl_xor(p, off);
        if (lane == 0) coef[j] = 1.0f / (1.0f + expf(-10.0f * p));
    }
    __syncthreads();
    int f = t & 127, half = t >> 7;           // half: nodes 0..31 / 32..63
    float acc = 0.f;
    for (int j = 0; j < 32; j++) {
        int jj = half * 32 + j;
        acc = fmaf(coef[jj], hp[(n0 + jj) * 128 + f], acc);
    }
    atomicAdd(&gf[g * 128 + f], acc);
}

// output writer: out[g][n][0:128]=h, out[g][n][128:256]=gf[g]; float4 flat
__global__ void k_out(const float* __restrict__ h, const float* __restrict__ gf,
                      float* __restrict__ out) {
    int idx = blockIdx.x * 256 + threadIdx.x;  // float4 slot, 64 per node
    int c4 = (idx & 63) * 4;
    int n = idx >> 6;                          // global node
    int g = n >> 9;
    float4 v = (c4 < 128) ? *(const float4*)(h + (size_t)n * 128 + c4)
                          : *(const float4*)(gf + g * 128 + (c4 - 128));
    *(float4*)(out + (size_t)idx * 4) = v;
}

// ---------------- host ----------------
extern "C" void kernel_launch(void* const* d_in, const int* in_sizes, int n_in,
                              void* d_out, int out_size, void* d_ws, size_t ws_size,
                              hipStream_t stream) {
    const float* x     = (const float*)d_in[0];
    const int*   esrc  = (const int*)d_in[1];
    const int*   edst  = (const int*)d_in[2];
    const float* W0    = (const float*)d_in[4];
    const float* b0    = (const float*)d_in[5];
    const float* Wr    = (const float*)d_in[6];
    const float* br    = (const float*)d_in[7];
    const float* gamma = (const float*)d_in[8];
    const float* beta  = (const float*)d_in[9];
    const float* Watt  = (const float*)d_in[10];
    float* out = (float*)d_out;
    float* ws  = (float*)d_ws;

    // workspace layout (float units)
    int*   cnt     = (int*)(ws + 0);          // NN
    int*   cursor  = (int*)(ws + 40960);      // NN
    int*   rp      = (int*)(ws + 81920);      // NN+1
    float* dinv    = ws + 122880;             // NN
    int*   csr_src = (int*)(ws + 163840);     // EE
    float* csr_w   = ws + 688128;             // EE
    float* stats   = ws + 1212416;            // LL*256
    float* tgbuf   = ws + 1217536;            // BG*128
    float* meansum = ws + 1225728;            // BG*128
    float* gf      = ws + 1233920;            // BG*128
    float* hw      = ws + 1245184;            // NN*DD fp32
    float* pre     = ws + 5439488;            // NN*DD fp32
    // end: 9633792 floats = 38.5 MB

    hipMemsetAsync(cnt, 0, NN * sizeof(int), stream);
    hipMemsetAsync(cursor, 0, NN * sizeof(int), stream);
    hipMemsetAsync(stats, 0, LL * 256 * sizeof(float), stream);
    hipMemsetAsync(meansum, 0, BG * 128 * sizeof(float), stream);
    hipMemsetAsync(gf, 0, BG * 128 * sizeof(float), stream);

    k_hist<<<EE / 256, 256, 0, stream>>>(edst, cnt);
    k_dinv<<<NN / 256, 256, 0, stream>>>(cnt, dinv);
    k_scan<<<1, 1024, 0, stream>>>(cnt, rp);
    k_fill<<<EE / 256, 256, 0, stream>>>(esrc, edst, dinv, rp, cursor, csr_src, csr_w);
    k_l0<<<(NN * DD) / 256, 256, 0, stream>>>(x, W0, hw);

    for (int l = 0; l < LL; l++) {
        const float* bias = (l == 0) ? b0 : br + (l - 1) * DD;
        k_agg<<<NN / 16, 256, 0, stream>>>(hw, dinv, rp, csr_src, csr_w, bias,
                                           pre, stats + l * 256);
        if (l < LL - 1)
            k_mm<<<NN / 64, 256, 0, stream>>>(pre, stats + l * 256, gamma + l * DD,
                                              beta + l * DD, Wr + l * DD * DD, hw);
        else
            k_bn_pool<<<NN / 64, 256, 0, stream>>>(pre, stats + l * 256, gamma + l * DD,
                                                   beta + l * DD, meansum);
    }
    k_tg<<<BG, 128, 0, stream>>>(meansum, Watt, tgbuf);
    k_coef_gf<<<NN / 64, 256, 0, stream>>>(pre, tgbuf, gf);
    k_out<<<NN * 64 / 256, 256, 0, stream>>>(pre, gf, out);
}

// Round 7
// 595.513 us; speedup vs baseline: 1.5912x; 1.5912x over previous
//
#include <hip/hip_runtime.h>
#include <hip/hip_bf16.h>
#include <math.h>

#define NN 32768      // B*NPG nodes
#define BG 64         // graphs
#define NPGC 512      // nodes per graph
#define DD 128        // hidden dim
#define EE 524288     // edges
#define LL 10         // layers
#define EPSF 1e-5f
#define PADK 72       // LDS row pitch (halfwords): 144B rows -> 2-way conflicts only (free, m136)

typedef __attribute__((ext_vector_type(8))) short short8;
typedef __attribute__((ext_vector_type(4))) float float4v;

static __device__ __forceinline__ unsigned short f2bf(float x) {
    __hip_bfloat16 b = __float2bfloat16(x);
    return *reinterpret_cast<unsigned short*>(&b);
}
static __device__ __forceinline__ float bf2f(unsigned short u) {
    unsigned int v = ((unsigned int)u) << 16;
    return __uint_as_float(v);
}
// split x into hi+lo bf16 (residual <= 2^-18 |x|)
static __device__ __forceinline__ void splitbf(float x, unsigned short& h, unsigned short& l) {
    unsigned short hh = f2bf(x);
    h = hh;
    l = f2bf(x - bf2f(hh));
}

// XCD swizzle (confirmed R4: FETCH 113MB->10.7MB): graph g work on blocks with
// blockIdx%8 == g%8 so each graph's slices stay in one XCD's L2.

// ---------------- prologue: degrees, CSR build ----------------
__global__ void k_hist(const int* __restrict__ dst, int* __restrict__ cnt) {
    int e = blockIdx.x * 256 + threadIdx.x;
    atomicAdd(&cnt[dst[e]], 1);
}

__global__ void k_dinv(const int* __restrict__ cnt, float* __restrict__ dinv) {
    int n = blockIdx.x * 256 + threadIdx.x;
    dinv[n] = rsqrtf(1.0f + (float)cnt[n]);
}

__global__ void k_scan(const int* __restrict__ cnt, int* __restrict__ rp) {
    __shared__ int s[1024];
    int t = threadIdx.x;
    int loc[32];
    int base = t * 32, tot = 0;
    for (int i = 0; i < 32; i++) { loc[i] = cnt[base + i]; tot += loc[i]; }
    s[t] = tot;
    __syncthreads();
    for (int off = 1; off < 1024; off <<= 1) {
        int add = (t >= off) ? s[t - off] : 0;
        __syncthreads();
        s[t] += add;
        __syncthreads();
    }
    int ex = (t == 0) ? 0 : s[t - 1];
    for (int i = 0; i < 32; i++) { rp[base + i] = ex; ex += loc[i]; }
    if (t == 1023) rp[NN] = ex;
}

__global__ void k_fill(const int* __restrict__ src, const int* __restrict__ dst,
                       const float* __restrict__ dinv, const int* __restrict__ rp,
                       int* __restrict__ cursor, int* __restrict__ csr_src,
                       float* __restrict__ csr_w) {
    int e = blockIdx.x * 256 + threadIdx.x;
    int d = dst[e], sx = src[e];
    int p = atomicAdd(&cursor[d], 1);
    int i = rp[d] + p;
    csr_src[i] = sx;
    csr_w[i] = dinv[sx] * dinv[d];
}

// dense adjacency rows -> hi/lo bf16 planes. One wave per dst row.
__global__ __launch_bounds__(256) void k_adj(const int* __restrict__ rp,
        const int* __restrict__ csr_src, const float* __restrict__ csr_w,
        const float* __restrict__ dinv, unsigned short* __restrict__ Adj_h,
        unsigned short* __restrict__ Adj_l) {
    __shared__ float rowbuf[4][512];
    int t = threadIdx.x, lane = t & 63, wv = t >> 6;
    int n = blockIdx.x * 4 + wv;
    int nl = n & 511;
    for (int j = lane; j < 512; j += 64) rowbuf[wv][j] = 0.f;
    __syncthreads();
    int e1 = rp[n + 1];
    for (int e = rp[n] + lane; e < e1; e += 64)
        atomicAdd(&rowbuf[wv][csr_src[e] & 511], csr_w[e]);
    __syncthreads();
    if (lane == 0) rowbuf[wv][nl] += dinv[n] * dinv[n];
    __syncthreads();
    size_t base = (size_t)n * 512;
    for (int j = lane; j < 512; j += 64) {
        unsigned short h, l;
        splitbf(rowbuf[wv][j], h, l);
        Adj_h[base + j] = h;
        Adj_l[base + j] = l;
    }
}

// Wt[l][f'][f] = split(W_rest[l][f][f'])
__global__ void k_wt(const float* __restrict__ Wr, unsigned short* __restrict__ Wt_h,
                     unsigned short* __restrict__ Wt_l) {
    int idx = blockIdx.x * 256 + threadIdx.x;   // over 9*16384
    int l = idx >> 14, rem = idx & 16383;
    int fp = rem >> 7, f = rem & 127;
    unsigned short h, lo;
    splitbf(Wr[l * 16384 + f * 128 + fp], h, lo);
    Wt_h[idx] = h;
    Wt_l[idx] = lo;
}

// layer-0: hwT[f][n] = split(x[n] * W0[f])
__global__ void k_l0(const float* __restrict__ x, const float* __restrict__ W0,
                     unsigned short* __restrict__ hwT_h, unsigned short* __restrict__ hwT_l) {
    int u = blockIdx.x * 256 + threadIdx.x;     // 128*4096 units of 8 nodes
    int f = u >> 12, n0 = (u & 4095) * 8;
    float w = W0[f];
    float4 xa = *(const float4*)(x + n0);
    float4 xb = *(const float4*)(x + n0 + 4);
    float v[8] = {xa.x * w, xa.y * w, xa.z * w, xa.w * w,
                  xb.x * w, xb.y * w, xb.z * w, xb.w * w};
    unsigned short uh[8], ul[8];
    #pragma unroll
    for (int i = 0; i < 8; i++) splitbf(v[i], uh[i], ul[i]);
    *(uint4*)(hwT_h + (size_t)f * NN + n0) = *(uint4*)uh;
    *(uint4*)(hwT_l + (size_t)f * NN + n0) = *(uint4*)ul;
}

// ---------------- aggregation as dense MFMA (split-precision) --------------
// pre = Adj_g @ hw_g + bias; 512 blocks (8/graph, XCD-swizzled), 64 dst x 128 f,
// K=512. 3-pass hi/lo: AhBh + AhBl + AlBh (err ~1e-5). BN stats in epilogue.
__global__ __launch_bounds__(256) void k_aggmm(const unsigned short* __restrict__ Adj_h,
        const unsigned short* __restrict__ Adj_l, const unsigned short* __restrict__ hwT_h,
        const unsigned short* __restrict__ hwT_l, const float* __restrict__ bias,
        float* __restrict__ pre, float* __restrict__ stats) {
    __shared__ unsigned short As_h[64 * PADK], As_l[64 * PADK];     // 18.4KB
    __shared__ unsigned short Bs_h[128 * PADK], Bs_l[128 * PADK];   // 36.9KB
    __shared__ float s_bias[128];
    __shared__ float s_sum[128], s_sq[128];
    int t = threadIdx.x, lane = t & 63, wv = t >> 6;
    int l15 = lane & 15, quad = lane >> 4;
    int b = blockIdx.x, r = b & 7, q = b >> 3;
    int g = r + 8 * (q & 7);
    int mb = (q >> 3) * 64;
    size_t arow = ((size_t)g * 512 + mb) * 512;
    size_t gcol = (size_t)g * 512;
    if (t < 128) { s_bias[t] = bias[t]; s_sum[t] = 0.f; s_sq[t] = 0.f; }
    float4v acc[8];
    #pragma unroll
    for (int i = 0; i < 8; i++) acc[i] = (float4v)0.f;

    for (int kc = 0; kc < 512; kc += 64) {
        __syncthreads();
        #pragma unroll
        for (int i = 0; i < 2; i++) {            // A planes: 512 16B-units each
            int u = t + i * 256;
            int row = u >> 3, ko = (u & 7) * 8;
            size_t go = arow + (size_t)row * 512 + kc + ko;
            *(uint4*)(&As_h[row * PADK + ko]) = *(const uint4*)(Adj_h + go);
            *(uint4*)(&As_l[row * PADK + ko]) = *(const uint4*)(Adj_l + go);
        }
        #pragma unroll
        for (int i = 0; i < 4; i++) {            // B planes: 1024 units each
            int u = t + i * 256;
            int f = u >> 3, ko = (u & 7) * 8;
            size_t go = (size_t)f * NN + gcol + kc + ko;
            *(uint4*)(&Bs_h[f * PADK + ko]) = *(const uint4*)(hwT_h + go);
            *(uint4*)(&Bs_l[f * PADK + ko]) = *(const uint4*)(hwT_l + go);
        }
        __syncthreads();
        int m0 = wv * 16;
        #pragma unroll
        for (int ks = 0; ks < 2; ks++) {
            int kb = ks * 32 + quad * 8;
            short8 ah = *(const short8*)(&As_h[(m0 + l15) * PADK + kb]);
            short8 al = *(const short8*)(&As_l[(m0 + l15) * PADK + kb]);
            #pragma unroll
            for (int nt = 0; nt < 8; nt++) {
                short8 bh = *(const short8*)(&Bs_h[(nt * 16 + l15) * PADK + kb]);
                short8 bl = *(const short8*)(&Bs_l[(nt * 16 + l15) * PADK + kb]);
                acc[nt] = __builtin_amdgcn_mfma_f32_16x16x32_bf16(ah, bh, acc[nt], 0, 0, 0);
                acc[nt] = __builtin_amdgcn_mfma_f32_16x16x32_bf16(ah, bl, acc[nt], 0, 0, 0);
                acc[nt] = __builtin_amdgcn_mfma_f32_16x16x32_bf16(al, bh, acc[nt], 0, 0, 0);
            }
        }
    }
    // epilogue: C/D layout col=lane&15 (feat), row=quad*4+reg (dst)
    int n0 = g * 512 + mb + wv * 16 + quad * 4;
    #pragma unroll
    for (int nt = 0; nt < 8; nt++) {
        int f = nt * 16 + l15;
        float bf = s_bias[f];
        float cs = 0.f, cq = 0.f;
        #pragma unroll
        for (int rg = 0; rg < 4; rg++) {
            float v = acc[nt][rg] + bf;
            pre[(size_t)(n0 + rg) * 128 + f] = v;
            cs += v;
            cq = fmaf(v, v, cq);
        }
        cs += __shfl_xor(cs, 16); cs += __shfl_xor(cs, 32);
        cq += __shfl_xor(cq, 16); cq += __shfl_xor(cq, 32);
        if (quad == 0) { atomicAdd(&s_sum[f], cs); atomicAdd(&s_sq[f], cq); }
    }
    __syncthreads();
    if (t < 128) {
        atomicAdd(&stats[t], s_sum[t]);
        atomicAdd(&stats[128 + t], s_sq[t]);
    }
}

// ---------------- feature matmul: hwT_next = (relu(bn(pre)) @ W)^T ---------
// C = Wt @ X^T, M=128 f', N=64 nodes, K=128, split-precision 3-pass.
__global__ __launch_bounds__(256) void k_mmT(const float* __restrict__ pre,
        const float* __restrict__ stats, const float* __restrict__ gamma,
        const float* __restrict__ beta, const unsigned short* __restrict__ Wt_h,
        const unsigned short* __restrict__ Wt_l, unsigned short* __restrict__ hwT_h,
        unsigned short* __restrict__ hwT_l) {
    __shared__ unsigned short Ws_h[128 * PADK], Ws_l[128 * PADK];  // 36.9KB
    __shared__ unsigned short Xs_h[64 * PADK], Xs_l[64 * PADK];    // 18.4KB
    __shared__ float scL[256];
    int t = threadIdx.x, lane = t & 63, wv = t >> 6;
    int l15 = lane & 15, quad = lane >> 4;
    int b = blockIdx.x, r = b & 7, q = b >> 3;
    int g = r + 8 * (q & 7);
    int nb = g * NPGC + (q >> 3) * 64;
    if (t < 128) {
        float mu = stats[t] * (1.0f / NN);
        float var = stats[128 + t] * (1.0f / NN) - mu * mu;
        float s = gamma[t] * rsqrtf(var + EPSF);
        scL[t] = s;
        scL[128 + t] = fmaf(-mu, s, beta[t]);
    }
    float4v acc[8];
    #pragma unroll
    for (int i = 0; i < 8; i++) acc[i] = (float4v)0.f;

    for (int kc = 0; kc < 128; kc += 64) {
        __syncthreads();    // first iter: publishes scL
        #pragma unroll
        for (int i = 0; i < 4; i++) {            // Wt planes: 1024 units each
            int u = t + i * 256;
            int fp = u >> 3, ko = (u & 7) * 8;
            int go = fp * 128 + kc + ko;
            *(uint4*)(&Ws_h[fp * PADK + ko]) = *(const uint4*)(Wt_h + go);
            *(uint4*)(&Ws_l[fp * PADK + ko]) = *(const uint4*)(Wt_l + go);
        }
        #pragma unroll
        for (int i = 0; i < 2; i++) {            // X: 512 units, bn+relu+split
            int u = t + i * 256;
            int n = u >> 3, fo = (u & 7) * 8;
            const float* pp = pre + (size_t)(nb + n) * 128 + kc + fo;
            float4 v0 = *(const float4*)(pp);
            float4 v1 = *(const float4*)(pp + 4);
            float4 s0 = *(const float4*)(&scL[kc + fo]);
            float4 s1 = *(const float4*)(&scL[kc + fo + 4]);
            float4 h0 = *(const float4*)(&scL[128 + kc + fo]);
            float4 h1 = *(const float4*)(&scL[128 + kc + fo + 4]);
            float v[8] = {fmaxf(fmaf(v0.x, s0.x, h0.x), 0.f),
                          fmaxf(fmaf(v0.y, s0.y, h0.y), 0.f),
                          fmaxf(fmaf(v0.z, s0.z, h0.z), 0.f),
                          fmaxf(fmaf(v0.w, s0.w, h0.w), 0.f),
                          fmaxf(fmaf(v1.x, s1.x, h1.x), 0.f),
                          fmaxf(fmaf(v1.y, s1.y, h1.y), 0.f),
                          fmaxf(fmaf(v1.z, s1.z, h1.z), 0.f),
                          fmaxf(fmaf(v1.w, s1.w, h1.w), 0.f)};
            unsigned short uh[8], ul[8];
            #pragma unroll
            for (int j = 0; j < 8; j++) splitbf(v[j], uh[j], ul[j]);
            *(uint4*)(&Xs_h[n * PADK + fo]) = *(uint4*)uh;
            *(uint4*)(&Xs_l[n * PADK + fo]) = *(uint4*)ul;
        }
        __syncthreads();
        int m0 = wv * 32;
        #pragma unroll
        for (int ks = 0; ks < 2; ks++) {
            int kb = ks * 32 + quad * 8;
            short8 a0h = *(const short8*)(&Ws_h[(m0 + l15) * PADK + kb]);
            short8 a0l = *(const short8*)(&Ws_l[(m0 + l15) * PADK + kb]);
            short8 a1h = *(const short8*)(&Ws_h[(m0 + 16 + l15) * PADK + kb]);
            short8 a1l = *(const short8*)(&Ws_l[(m0 + 16 + l15) * PADK + kb]);
            #pragma unroll
            for (int nt = 0; nt < 4; nt++) {
                short8 bh = *(const short8*)(&Xs_h[(nt * 16 + l15) * PADK + kb]);
                short8 bl = *(const short8*)(&Xs_l[(nt * 16 + l15) * PADK + kb]);
                acc[nt]     = __builtin_amdgcn_mfma_f32_16x16x32_bf16(a0h, bh, acc[nt], 0, 0, 0);
                acc[nt]     = __builtin_amdgcn_mfma_f32_16x16x32_bf16(a0h, bl, acc[nt], 0, 0, 0);
                acc[nt]     = __builtin_amdgcn_mfma_f32_16x16x32_bf16(a0l, bh, acc[nt], 0, 0, 0);
                acc[4 + nt] = __builtin_amdgcn_mfma_f32_16x16x32_bf16(a1h, bh, acc[4 + nt], 0, 0, 0);
                acc[4 + nt] = __builtin_amdgcn_mfma_f32_16x16x32_bf16(a1h, bl, acc[4 + nt], 0, 0, 0);
                acc[4 + nt] = __builtin_amdgcn_mfma_f32_16x16x32_bf16(a1l, bh, acc[4 + nt], 0, 0, 0);
            }
        }
    }
    #pragma unroll
    for (int mt = 0; mt < 2; mt++) {
        #pragma unroll
        for (int nt = 0; nt < 4; nt++) {
            int n = nb + nt * 16 + l15;
            int fp0 = wv * 32 + mt * 16 + quad * 4;
            float4v a = acc[mt * 4 + nt];
            #pragma unroll
            for (int rg = 0; rg < 4; rg++) {
                unsigned short h, lo;
                splitbf(a[rg], h, lo);
                hwT_h[(size_t)(fp0 + rg) * NN + n] = h;
                hwT_l[(size_t)(fp0 + rg) * NN + n] = lo;
            }
        }
    }
}

// last layer: BN+ReLU in-place + per-graph column sums. 512 blocks, swizzled.
__global__ __launch_bounds__(256) void k_bn_pool(float* __restrict__ pre,
        const float* __restrict__ stats, const float* __restrict__ gamma,
        const float* __restrict__ beta, float* __restrict__ meansum) {
    __shared__ float ssum[256];
    __shared__ float scL[256];
    int t = threadIdx.x;
    int b = blockIdx.x, r = b & 7, q = b >> 3;
    int g = r + 8 * (q & 7);
    int nb = g * NPGC + (q >> 3) * 64;
    if (t < 128) {
        float mu = stats[t] * (1.0f / NN);
        float var = stats[128 + t] * (1.0f / NN) - mu * mu;
        float s = gamma[t] * rsqrtf(var + EPSF);
        scL[t] = s;
        scL[128 + t] = fmaf(-mu, s, beta[t]);
    }
    __syncthreads();
    int f = t & 127;
    float s = scL[f], sh = scL[128 + f];
    float lsum = 0.f;
    int base = nb * 128;
    for (int i = 0; i < 32; i++) {
        int idx = base + i * 256 + t;
        float v = fmaxf(fmaf(pre[idx], s, sh), 0.f);
        pre[idx] = v;
        lsum += v;
    }
    ssum[t] = lsum;
    __syncthreads();
    if (t < 128) atomicAdd(&meansum[g * 128 + f], ssum[t] + ssum[t + 128]);
}

// tg = tanh((meansum/512) @ W_att), per graph
__global__ void k_tg(const float* __restrict__ meansum, const float* __restrict__ Watt,
                     float* __restrict__ tg) {
    __shared__ float m[128];
    int g = blockIdx.x, t = threadIdx.x;  // 128 threads
    m[t] = meansum[g * 128 + t] * (1.0f / NPGC);
    __syncthreads();
    float a2 = 0.f;
    for (int k = 0; k < 128; k++) a2 = fmaf(m[k], Watt[k * 128 + t], a2);
    tg[g * 128 + t] = tanhf(a2);
}

// coefs = sigmoid(10*<h,tg>) and gf += coef*h. 512 blocks, swizzled.
__global__ __launch_bounds__(256) void k_coef_gf(const float* __restrict__ h,
        const float* __restrict__ tg, float* __restrict__ gf) {
    __shared__ float tgs[128];
    __shared__ float coef[64];
    int t = threadIdx.x;
    int b = blockIdx.x, r = b & 7, q = b >> 3;
    int g = r + 8 * (q & 7);
    int n0 = (q >> 3) * 64;
    if (t < 128) tgs[t] = tg[g * 128 + t];
    __syncthreads();
    int wid = t >> 6, lane = t & 63;
    const float* hp = h + (size_t)g * NPGC * 128;
    for (int j = wid; j < 64; j += 4) {
        int n = n0 + j;
        float p = hp[n * 128 + lane] * tgs[lane] + hp[n * 128 + 64 + lane] * tgs[64 + lane];
        for (int off = 32; off; off >>= 1) p += __shfl_xor(p, off);
        if (lane == 0) coef[j] = 1.0f / (1.0f + expf(-10.0f * p));
    }
    __syncthreads();
    int f = t & 127, half = t >> 7;
    float acc = 0.f;
    for (int j = 0; j < 32; j++) {
        int jj = half * 32 + j;
        acc = fmaf(coef[jj], hp[(n0 + jj) * 128 + f], acc);
    }
    atomicAdd(&gf[g * 128 + f], acc);
}

// output writer
__global__ void k_out(const float* __restrict__ h, const float* __restrict__ gf,
                      float* __restrict__ out) {
    int idx = blockIdx.x * 256 + threadIdx.x;
    int c4 = (idx & 63) * 4;
    int n = idx >> 6;
    int g = n >> 9;
    float4 v = (c4 < 128) ? *(const float4*)(h + (size_t)n * 128 + c4)
                          : *(const float4*)(gf + g * 128 + (c4 - 128));
    *(float4*)(out + (size_t)idx * 4) = v;
}

// ---------------- host ----------------
extern "C" void kernel_launch(void* const* d_in, const int* in_sizes, int n_in,
                              void* d_out, int out_size, void* d_ws, size_t ws_size,
                              hipStream_t stream) {
    const float* x     = (const float*)d_in[0];
    const int*   esrc  = (const int*)d_in[1];
    const int*   edst  = (const int*)d_in[2];
    const float* W0    = (const float*)d_in[4];
    const float* b0    = (const float*)d_in[5];
    const float* Wr    = (const float*)d_in[6];
    const float* br    = (const float*)d_in[7];
    const float* gamma = (const float*)d_in[8];
    const float* beta  = (const float*)d_in[9];
    const float* Watt  = (const float*)d_in[10];
    float* out = (float*)d_out;
    float* ws  = (float*)d_ws;

    // workspace layout (float units), total ~102MB
    int*   cnt     = (int*)(ws + 0);             // 32768
    int*   cursor  = (int*)(ws + 32768);         // 32768
    int*   rp      = (int*)(ws + 65536);         // 32769
    float* dinv    = ws + 98560;                 // 32768
    float* stats   = ws + 131584;                // 2560
    float* tgbuf   = ws + 134400;                // 8192
    float* meansum = ws + 142592;                // 8192
    float* gf      = ws + 150784;                // 8192
    unsigned short* Wt_h  = (unsigned short*)(ws + 159232);   // 147456 sh = 73728 f
    unsigned short* Wt_l  = (unsigned short*)(ws + 232960);
    unsigned short* hwT_h = (unsigned short*)(ws + 306688);   // 4.19M sh = 2097152 f
    unsigned short* hwT_l = (unsigned short*)(ws + 2403840);
    unsigned short* Adj_h = (unsigned short*)(ws + 4500992);  // 16.8M sh = 8388608 f
    unsigned short* Adj_l = (unsigned short*)(ws + 12889600);
    float* pre     = ws + 21278208;              // NN*128 = 4194304 f
    // csr buffers alias pre (only used before k_adj; pre first written by k_aggmm)
    int*   csr_src = (int*)pre;                  // EE ints
    float* csr_w   = pre + EE;                   // EE floats
    // end: 25472512 floats = 101.9MB

    hipMemsetAsync(cnt, 0, NN * sizeof(int), stream);
    hipMemsetAsync(cursor, 0, NN * sizeof(int), stream);
    hipMemsetAsync(stats, 0, LL * 256 * sizeof(float), stream);
    hipMemsetAsync(meansum, 0, BG * 128 * sizeof(float), stream);
    hipMemsetAsync(gf, 0, BG * 128 * sizeof(float), stream);

    k_hist<<<EE / 256, 256, 0, stream>>>(edst, cnt);
    k_dinv<<<NN / 256, 256, 0, stream>>>(cnt, dinv);
    k_scan<<<1, 1024, 0, stream>>>(cnt, rp);
    k_fill<<<EE / 256, 256, 0, stream>>>(esrc, edst, dinv, rp, cursor, csr_src, csr_w);
    k_adj<<<NN / 4, 256, 0, stream>>>(rp, csr_src, csr_w, dinv, Adj_h, Adj_l);
    k_wt<<<9 * 16384 / 256, 256, 0, stream>>>(Wr, Wt_h, Wt_l);
    k_l0<<<128 * (NN / 8) / 256, 256, 0, stream>>>(x, W0, hwT_h, hwT_l);

    for (int l = 0; l < LL; l++) {
        const float* bias = (l == 0) ? b0 : br + (l - 1) * DD;
        k_aggmm<<<NN / 64, 256, 0, stream>>>(Adj_h, Adj_l, hwT_h, hwT_l, bias,
                                             pre, stats + l * 256);
        if (l < LL - 1)
            k_mmT<<<NN / 64, 256, 0, stream>>>(pre, stats + l * 256, gamma + l * DD,
                                               beta + l * DD, Wt_h + l * 16384,
                                               Wt_l + l * 16384, hwT_h, hwT_l);
        else
            k_bn_pool<<<NN / 64, 256, 0, stream>>>(pre, stats + l * 256, gamma + l * DD,
                                                   beta + l * DD, meansum);
    }
    k_tg<<<BG, 128, 0, stream>>>(meansum, Watt, tgbuf);
    k_coef_gf<<<NN / 64, 256, 0, stream>>>(pre, tgbuf, gf);
    k_out<<<NN * 64 / 256, 256, 0, stream>>>(pre, gf, out);
}

// Round 8
// 538.858 us; speedup vs baseline: 1.7585x; 1.1051x over previous
//
#include <hip/hip_runtime.h>
#include <hip/hip_bf16.h>
#include <math.h>

#define NN 32768      // B*NPG nodes
#define BG 64         // graphs
#define NPGC 512      // nodes per graph
#define DD 128        // hidden dim
#define EE 524288     // edges
#define LL 10         // layers
#define EPSF 1e-5f
#define PADK 72       // LDS row pitch (halfwords): 144B rows -> 2-way conflicts only (free, m136)

typedef __attribute__((ext_vector_type(8))) short short8;
typedef __attribute__((ext_vector_type(4))) float float4v;

static __device__ __forceinline__ unsigned short f2bf(float x) {
    __hip_bfloat16 b = __float2bfloat16(x);
    return *reinterpret_cast<unsigned short*>(&b);
}
static __device__ __forceinline__ float bf2f(unsigned short u) {
    unsigned int v = ((unsigned int)u) << 16;
    return __uint_as_float(v);
}
// split x into hi+lo bf16 (residual <= 2^-18 |x|)
static __device__ __forceinline__ void splitbf(float x, unsigned short& h, unsigned short& l) {
    unsigned short hh = f2bf(x);
    h = hh;
    l = f2bf(x - bf2f(hh));
}

// XCD swizzle (confirmed R4): graph g work on blocks with blockIdx%8 == g%8.
// Aggregation uses Adj = diag(dinv) M diag(dinv), M = A+I integer -> exact bf16
// A-operand, so aggregation needs only 2 MFMA passes (M*Bh + M*Bl).

// ---------------- prologue ----------------
// histogram: M counts + degree
__global__ void k_histM(const int* __restrict__ src, const int* __restrict__ dst,
                        int* __restrict__ Mint, int* __restrict__ cnt) {
    int e = blockIdx.x * 256 + threadIdx.x;
    int d = dst[e], s = src[e] & 511;
    atomicAdd(&Mint[(size_t)d * 512 + s], 1);
    atomicAdd(&cnt[d], 1);
}

__global__ void k_dinv(const int* __restrict__ cnt, float* __restrict__ dinv) {
    int n = blockIdx.x * 256 + threadIdx.x;
    dinv[n] = rsqrtf(1.0f + (float)cnt[n]);
}

// Mint -> bf16 M rows with +1 on the (local) diagonal. 4 elems/thread.
__global__ void k_conv(const int* __restrict__ Mint, unsigned short* __restrict__ Mh) {
    int idx = (blockIdx.x * 256 + threadIdx.x) * 4;
    int4 v = *(const int4*)(Mint + idx);
    int row = idx >> 9;              // global node
    int diag = row & 511;            // local diagonal column
    int cb = idx & 511;
    unsigned short us[4];
    us[0] = f2bf((float)(v.x + (cb + 0 == diag ? 1 : 0)));
    us[1] = f2bf((float)(v.y + (cb + 1 == diag ? 1 : 0)));
    us[2] = f2bf((float)(v.z + (cb + 2 == diag ? 1 : 0)));
    us[3] = f2bf((float)(v.w + (cb + 3 == diag ? 1 : 0)));
    *(uint2*)(Mh + idx) = *(uint2*)us;
}

// Wt[l][f'][f] = split(W_rest[l][f][f'])
__global__ void k_wt(const float* __restrict__ Wr, unsigned short* __restrict__ Wt_h,
                     unsigned short* __restrict__ Wt_l) {
    int idx = blockIdx.x * 256 + threadIdx.x;   // over 9*16384
    int l = idx >> 14, rem = idx & 16383;
    int fp = rem >> 7, f = rem & 127;
    unsigned short h, lo;
    splitbf(Wr[l * 16384 + f * 128 + fp], h, lo);
    Wt_h[idx] = h;
    Wt_l[idx] = lo;
}

// layer-0: hwT[f][n] = split(dinv[n] * x[n] * W0[f])
__global__ void k_l0(const float* __restrict__ x, const float* __restrict__ W0,
                     const float* __restrict__ dinv,
                     unsigned short* __restrict__ hwT_h, unsigned short* __restrict__ hwT_l) {
    int u = blockIdx.x * 256 + threadIdx.x;     // 128*4096 units of 8 nodes
    int f = u >> 12, n0 = (u & 4095) * 8;
    float w = W0[f];
    float4 xa = *(const float4*)(x + n0);
    float4 xb = *(const float4*)(x + n0 + 4);
    float4 da = *(const float4*)(dinv + n0);
    float4 db = *(const float4*)(dinv + n0 + 4);
    float v[8] = {xa.x * w * da.x, xa.y * w * da.y, xa.z * w * da.z, xa.w * w * da.w,
                  xb.x * w * db.x, xb.y * w * db.y, xb.z * w * db.z, xb.w * w * db.w};
    unsigned short uh[8], ul[8];
    #pragma unroll
    for (int i = 0; i < 8; i++) splitbf(v[i], uh[i], ul[i]);
    *(uint4*)(hwT_h + (size_t)f * NN + n0) = *(uint4*)uh;
    *(uint4*)(hwT_l + (size_t)f * NN + n0) = *(uint4*)ul;
}

// ---------------- aggregation: pre = diag(dinv) (M @ hwT^T) + bias ---------
// 512 blocks (8/graph, XCD-swizzled): 64 dst x 128 feat, K=512, BK=64.
// Wave covers 64 dst x 32 feat (mt=4, nt=2): MFMA:ds_read = 2:1. 2-pass
// (M exact bf16). BN stats in epilogue (per-f atomics, feats disjoint by wave).
__global__ __launch_bounds__(256) void k_aggmm(const unsigned short* __restrict__ Mh,
        const unsigned short* __restrict__ hwT_h, const unsigned short* __restrict__ hwT_l,
        const float* __restrict__ dinv, const float* __restrict__ bias,
        float* __restrict__ pre, float* __restrict__ stats) {
    __shared__ unsigned short As[64 * PADK];                       // 9.2KB
    __shared__ unsigned short Bs_h[128 * PADK], Bs_l[128 * PADK];  // 36.9KB
    int t = threadIdx.x, lane = t & 63, wv = t >> 6;
    int l15 = lane & 15, quad = lane >> 4;
    int b = blockIdx.x, r = b & 7, q = b >> 3;
    int g = r + 8 * (q & 7);
    int mb = (q >> 3) * 64;
    size_t arow = ((size_t)g * 512 + mb) * 512;
    size_t gcol = (size_t)g * 512;
    float4v acc[8];          // [mt][nt]
    #pragma unroll
    for (int i = 0; i < 8; i++) acc[i] = (float4v)0.f;

    for (int kc = 0; kc < 512; kc += 64) {
        __syncthreads();
        #pragma unroll
        for (int i = 0; i < 2; i++) {            // A: 512 16B-units
            int u = t + i * 256;
            int row = u >> 3, ko = (u & 7) * 8;
            *(uint4*)(&As[row * PADK + ko]) =
                *(const uint4*)(Mh + arow + (size_t)row * 512 + kc + ko);
        }
        #pragma unroll
        for (int i = 0; i < 4; i++) {            // B planes: 1024 units each
            int u = t + i * 256;
            int f = u >> 3, ko = (u & 7) * 8;
            size_t go = (size_t)f * NN + gcol + kc + ko;
            *(uint4*)(&Bs_h[f * PADK + ko]) = *(const uint4*)(hwT_h + go);
            *(uint4*)(&Bs_l[f * PADK + ko]) = *(const uint4*)(hwT_l + go);
        }
        __syncthreads();
        int f0 = wv * 32;
        #pragma unroll
        for (int ks = 0; ks < 2; ks++) {
            int kb = ks * 32 + quad * 8;
            short8 a0 = *(const short8*)(&As[(l15) * PADK + kb]);
            short8 a1 = *(const short8*)(&As[(16 + l15) * PADK + kb]);
            short8 a2 = *(const short8*)(&As[(32 + l15) * PADK + kb]);
            short8 a3 = *(const short8*)(&As[(48 + l15) * PADK + kb]);
            #pragma unroll
            for (int nt = 0; nt < 2; nt++) {
                short8 bh = *(const short8*)(&Bs_h[(f0 + nt * 16 + l15) * PADK + kb]);
                short8 bl = *(const short8*)(&Bs_l[(f0 + nt * 16 + l15) * PADK + kb]);
                acc[0 + nt] = __builtin_amdgcn_mfma_f32_16x16x32_bf16(a0, bh, acc[0 + nt], 0, 0, 0);
                acc[0 + nt] = __builtin_amdgcn_mfma_f32_16x16x32_bf16(a0, bl, acc[0 + nt], 0, 0, 0);
                acc[2 + nt] = __builtin_amdgcn_mfma_f32_16x16x32_bf16(a1, bh, acc[2 + nt], 0, 0, 0);
                acc[2 + nt] = __builtin_amdgcn_mfma_f32_16x16x32_bf16(a1, bl, acc[2 + nt], 0, 0, 0);
                acc[4 + nt] = __builtin_amdgcn_mfma_f32_16x16x32_bf16(a2, bh, acc[4 + nt], 0, 0, 0);
                acc[4 + nt] = __builtin_amdgcn_mfma_f32_16x16x32_bf16(a2, bl, acc[4 + nt], 0, 0, 0);
                acc[6 + nt] = __builtin_amdgcn_mfma_f32_16x16x32_bf16(a3, bh, acc[6 + nt], 0, 0, 0);
                acc[6 + nt] = __builtin_amdgcn_mfma_f32_16x16x32_bf16(a3, bl, acc[6 + nt], 0, 0, 0);
            }
        }
    }
    // epilogue: C/D col=l15 -> feat, row=quad*4+rg -> dst-local (verified R7)
    int gbase = g * 512 + mb;
    #pragma unroll
    for (int nt = 0; nt < 2; nt++) {
        int f = wv * 32 + nt * 16 + l15;
        float bf = bias[f];
        float cs = 0.f, cq = 0.f;
        #pragma unroll
        for (int mt = 0; mt < 4; mt++) {
            int n0 = gbase + mt * 16 + quad * 4;
            float4 dv = *(const float4*)(dinv + n0);
            float4v a = acc[mt * 2 + nt];
            float v0 = fmaf(dv.x, a[0], bf);
            float v1 = fmaf(dv.y, a[1], bf);
            float v2 = fmaf(dv.z, a[2], bf);
            float v3 = fmaf(dv.w, a[3], bf);
            pre[(size_t)(n0 + 0) * 128 + f] = v0;
            pre[(size_t)(n0 + 1) * 128 + f] = v1;
            pre[(size_t)(n0 + 2) * 128 + f] = v2;
            pre[(size_t)(n0 + 3) * 128 + f] = v3;
            cs += v0 + v1 + v2 + v3;
            cq = fmaf(v0, v0, cq); cq = fmaf(v1, v1, cq);
            cq = fmaf(v2, v2, cq); cq = fmaf(v3, v3, cq);
        }
        cs += __shfl_xor(cs, 16); cs += __shfl_xor(cs, 32);
        cq += __shfl_xor(cq, 16); cq += __shfl_xor(cq, 32);
        if (quad == 0) {
            atomicAdd(&stats[f], cs);
            atomicAdd(&stats[128 + f], cq);
        }
    }
}

// ---------------- feature matmul: hwT_next = dinv ⊙ (relu(bn(pre)) @ W)^T --
// C = Wt @ X^T, M=128 f', N=64 nodes, K=128, split-precision 3-pass.
__global__ __launch_bounds__(256) void k_mmT(const float* __restrict__ pre,
        const float* __restrict__ stats, const float* __restrict__ gamma,
        const float* __restrict__ beta, const float* __restrict__ dinv,
        const unsigned short* __restrict__ Wt_h, const unsigned short* __restrict__ Wt_l,
        unsigned short* __restrict__ hwT_h, unsigned short* __restrict__ hwT_l) {
    __shared__ unsigned short Ws_h[128 * PADK], Ws_l[128 * PADK];  // 36.9KB
    __shared__ unsigned short Xs_h[64 * PADK], Xs_l[64 * PADK];    // 18.4KB
    __shared__ float scL[256];
    int t = threadIdx.x, lane = t & 63, wv = t >> 6;
    int l15 = lane & 15, quad = lane >> 4;
    int b = blockIdx.x, r = b & 7, q = b >> 3;
    int g = r + 8 * (q & 7);
    int nb = g * NPGC + (q >> 3) * 64;
    if (t < 128) {
        float mu = stats[t] * (1.0f / NN);
        float var = stats[128 + t] * (1.0f / NN) - mu * mu;
        float s = gamma[t] * rsqrtf(var + EPSF);
        scL[t] = s;
        scL[128 + t] = fmaf(-mu, s, beta[t]);
    }
    float4v acc[8];
    #pragma unroll
    for (int i = 0; i < 8; i++) acc[i] = (float4v)0.f;

    for (int kc = 0; kc < 128; kc += 64) {
        __syncthreads();    // first iter: publishes scL
        #pragma unroll
        for (int i = 0; i < 4; i++) {            // Wt planes: 1024 units each
            int u = t + i * 256;
            int fp = u >> 3, ko = (u & 7) * 8;
            int go = fp * 128 + kc + ko;
            *(uint4*)(&Ws_h[fp * PADK + ko]) = *(const uint4*)(Wt_h + go);
            *(uint4*)(&Ws_l[fp * PADK + ko]) = *(const uint4*)(Wt_l + go);
        }
        #pragma unroll
        for (int i = 0; i < 2; i++) {            // X: 512 units, bn+relu+split
            int u = t + i * 256;
            int n = u >> 3, fo = (u & 7) * 8;
            const float* pp = pre + (size_t)(nb + n) * 128 + kc + fo;
            float4 v0 = *(const float4*)(pp);
            float4 v1 = *(const float4*)(pp + 4);
            float4 s0 = *(const float4*)(&scL[kc + fo]);
            float4 s1 = *(const float4*)(&scL[kc + fo + 4]);
            float4 h0 = *(const float4*)(&scL[128 + kc + fo]);
            float4 h1 = *(const float4*)(&scL[128 + kc + fo + 4]);
            float v[8] = {fmaxf(fmaf(v0.x, s0.x, h0.x), 0.f),
                          fmaxf(fmaf(v0.y, s0.y, h0.y), 0.f),
                          fmaxf(fmaf(v0.z, s0.z, h0.z), 0.f),
                          fmaxf(fmaf(v0.w, s0.w, h0.w), 0.f),
                          fmaxf(fmaf(v1.x, s1.x, h1.x), 0.f),
                          fmaxf(fmaf(v1.y, s1.y, h1.y), 0.f),
                          fmaxf(fmaf(v1.z, s1.z, h1.z), 0.f),
                          fmaxf(fmaf(v1.w, s1.w, h1.w), 0.f)};
            unsigned short uh[8], ul[8];
            #pragma unroll
            for (int j = 0; j < 8; j++) splitbf(v[j], uh[j], ul[j]);
            *(uint4*)(&Xs_h[n * PADK + fo]) = *(uint4*)uh;
            *(uint4*)(&Xs_l[n * PADK + fo]) = *(uint4*)ul;
        }
        __syncthreads();
        int m0 = wv * 32;
        #pragma unroll
        for (int ks = 0; ks < 2; ks++) {
            int kb = ks * 32 + quad * 8;
            short8 a0h = *(const short8*)(&Ws_h[(m0 + l15) * PADK + kb]);
            short8 a0l = *(const short8*)(&Ws_l[(m0 + l15) * PADK + kb]);
            short8 a1h = *(const short8*)(&Ws_h[(m0 + 16 + l15) * PADK + kb]);
            short8 a1l = *(const short8*)(&Ws_l[(m0 + 16 + l15) * PADK + kb]);
            #pragma unroll
            for (int nt = 0; nt < 4; nt++) {
                short8 bh = *(const short8*)(&Xs_h[(nt * 16 + l15) * PADK + kb]);
                short8 bl = *(const short8*)(&Xs_l[(nt * 16 + l15) * PADK + kb]);
                acc[nt]     = __builtin_amdgcn_mfma_f32_16x16x32_bf16(a0h, bh, acc[nt], 0, 0, 0);
                acc[nt]     = __builtin_amdgcn_mfma_f32_16x16x32_bf16(a0h, bl, acc[nt], 0, 0, 0);
                acc[nt]     = __builtin_amdgcn_mfma_f32_16x16x32_bf16(a0l, bh, acc[nt], 0, 0, 0);
                acc[4 + nt] = __builtin_amdgcn_mfma_f32_16x16x32_bf16(a1h, bh, acc[4 + nt], 0, 0, 0);
                acc[4 + nt] = __builtin_amdgcn_mfma_f32_16x16x32_bf16(a1h, bl, acc[4 + nt], 0, 0, 0);
                acc[4 + nt] = __builtin_amdgcn_mfma_f32_16x16x32_bf16(a1l, bh, acc[4 + nt], 0, 0, 0);
            }
        }
    }
    #pragma unroll
    for (int mt = 0; mt < 2; mt++) {
        #pragma unroll
        for (int nt = 0; nt < 4; nt++) {
            int n = nb + nt * 16 + l15;
            float dv = dinv[n];
            int fp0 = wv * 32 + mt * 16 + quad * 4;
            float4v a = acc[mt * 4 + nt];
            #pragma unroll
            for (int rg = 0; rg < 4; rg++) {
                unsigned short h, lo;
                splitbf(dv * a[rg], h, lo);
                hwT_h[(size_t)(fp0 + rg) * NN + n] = h;
                hwT_l[(size_t)(fp0 + rg) * NN + n] = lo;
            }
        }
    }
}

// last layer: BN+ReLU in-place + per-graph column sums. 512 blocks, swizzled.
__global__ __launch_bounds__(256) void k_bn_pool(float* __restrict__ pre,
        const float* __restrict__ stats, const float* __restrict__ gamma,
        const float* __restrict__ beta, float* __restrict__ meansum) {
    __shared__ float ssum[256];
    __shared__ float scL[256];
    int t = threadIdx.x;
    int b = blockIdx.x, r = b & 7, q = b >> 3;
    int g = r + 8 * (q & 7);
    int nb = g * NPGC + (q >> 3) * 64;
    if (t < 128) {
        float mu = stats[t] * (1.0f / NN);
        float var = stats[128 + t] * (1.0f / NN) - mu * mu;
        float s = gamma[t] * rsqrtf(var + EPSF);
        scL[t] = s;
        scL[128 + t] = fmaf(-mu, s, beta[t]);
    }
    __syncthreads();
    int f = t & 127;
    float s = scL[f], sh = scL[128 + f];
    float lsum = 0.f;
    int base = nb * 128;
    for (int i = 0; i < 32; i++) {
        int idx = base + i * 256 + t;
        float v = fmaxf(fmaf(pre[idx], s, sh), 0.f);
        pre[idx] = v;
        lsum += v;
    }
    ssum[t] = lsum;
    __syncthreads();
    if (t < 128) atomicAdd(&meansum[g * 128 + f], ssum[t] + ssum[t + 128]);
}

// tg = tanh((meansum/512) @ W_att), per graph
__global__ void k_tg(const float* __restrict__ meansum, const float* __restrict__ Watt,
                     float* __restrict__ tg) {
    __shared__ float m[128];
    int g = blockIdx.x, t = threadIdx.x;  // 128 threads
    m[t] = meansum[g * 128 + t] * (1.0f / NPGC);
    __syncthreads();
    float a2 = 0.f;
    for (int k = 0; k < 128; k++) a2 = fmaf(m[k], Watt[k * 128 + t], a2);
    tg[g * 128 + t] = tanhf(a2);
}

// coefs = sigmoid(10*<h,tg>) and gf += coef*h. 512 blocks, swizzled.
__global__ __launch_bounds__(256) void k_coef_gf(const float* __restrict__ h,
        const float* __restrict__ tg, float* __restrict__ gf) {
    __shared__ float tgs[128];
    __shared__ float coef[64];
    int t = threadIdx.x;
    int b = blockIdx.x, r = b & 7, q = b >> 3;
    int g = r + 8 * (q & 7);
    int n0 = (q >> 3) * 64;
    if (t < 128) tgs[t] = tg[g * 128 + t];
    __syncthreads();
    int wid = t >> 6, lane = t & 63;
    const float* hp = h + (size_t)g * NPGC * 128;
    for (int j = wid; j < 64; j += 4) {
        int n = n0 + j;
        float p = hp[n * 128 + lane] * tgs[lane] + hp[n * 128 + 64 + lane] * tgs[64 + lane];
        for (int off = 32; off; off >>= 1) p += __shfl_xor(p, off);
        if (lane == 0) coef[j] = 1.0f / (1.0f + expf(-10.0f * p));
    }
    __syncthreads();
    int f = t & 127, half = t >> 7;
    float acc = 0.f;
    for (int j = 0; j < 32; j++) {
        int jj = half * 32 + j;
        acc = fmaf(coef[jj], hp[(n0 + jj) * 128 + f], acc);
    }
    atomicAdd(&gf[g * 128 + f], acc);
}

// output writer
__global__ void k_out(const float* __restrict__ h, const float* __restrict__ gf,
                      float* __restrict__ out) {
    int idx = blockIdx.x * 256 + threadIdx.x;
    int c4 = (idx & 63) * 4;
    int n = idx >> 6;
    int g = n >> 9;
    float4 v = (c4 < 128) ? *(const float4*)(h + (size_t)n * 128 + c4)
                          : *(const float4*)(gf + g * 128 + (c4 - 128));
    *(float4*)(out + (size_t)idx * 4) = v;
}

// ---------------- host ----------------
extern "C" void kernel_launch(void* const* d_in, const int* in_sizes, int n_in,
                              void* d_out, int out_size, void* d_ws, size_t ws_size,
                              hipStream_t stream) {
    const float* x     = (const float*)d_in[0];
    const int*   esrc  = (const int*)d_in[1];
    const int*   edst  = (const int*)d_in[2];
    const float* W0    = (const float*)d_in[4];
    const float* b0    = (const float*)d_in[5];
    const float* Wr    = (const float*)d_in[6];
    const float* br    = (const float*)d_in[7];
    const float* gamma = (const float*)d_in[8];
    const float* beta  = (const float*)d_in[9];
    const float* Watt  = (const float*)d_in[10];
    float* out = (float*)d_out;
    float* ws  = (float*)d_ws;

    // workspace layout (float units), ~118MB
    int*   cnt     = (int*)(ws + 0);             // 32768
    float* dinv    = ws + 32768;                 // 32768
    float* stats   = ws + 65536;                 // 2560
    float* tgbuf   = ws + 68096;                 // 8192
    float* meansum = ws + 76288;                 // 8192
    float* gf      = ws + 84480;                 // 8192
    unsigned short* Wt_h  = (unsigned short*)(ws + 92672);     // 147456 sh
    unsigned short* Wt_l  = (unsigned short*)(ws + 166400);
    unsigned short* hwT_h = (unsigned short*)(ws + 240128);    // 4.19M sh
    unsigned short* hwT_l = (unsigned short*)(ws + 2337280);
    unsigned short* Mh    = (unsigned short*)(ws + 4434432);   // NN*512 sh
    int*   Mint    = (int*)(ws + 12823040);      // NN*512 ints (freed after k_conv)
    float* pre     = ws + 12823040;              // aliases Mint; first write in k_aggmm
    // end: 29600256 floats = 118.4MB

    hipMemsetAsync(cnt, 0, NN * sizeof(int), stream);
    hipMemsetAsync(stats, 0, LL * 256 * sizeof(float), stream);
    hipMemsetAsync(meansum, 0, BG * 128 * sizeof(float), stream);
    hipMemsetAsync(gf, 0, BG * 128 * sizeof(float), stream);
    hipMemsetAsync(Mint, 0, (size_t)NN * 512 * sizeof(int), stream);

    k_histM<<<EE / 256, 256, 0, stream>>>(esrc, edst, Mint, cnt);
    k_dinv<<<NN / 256, 256, 0, stream>>>(cnt, dinv);
    k_conv<<<NN * 512 / 1024, 256, 0, stream>>>(Mint, Mh);
    k_wt<<<9 * 16384 / 256, 256, 0, stream>>>(Wr, Wt_h, Wt_l);
    k_l0<<<128 * (NN / 8) / 256, 256, 0, stream>>>(x, W0, dinv, hwT_h, hwT_l);

    for (int l = 0; l < LL; l++) {
        const float* bias = (l == 0) ? b0 : br + (l - 1) * DD;
        k_aggmm<<<NN / 64, 256, 0, stream>>>(Mh, hwT_h, hwT_l, dinv, bias,
                                             pre, stats + l * 256);
        if (l < LL - 1)
            k_mmT<<<NN / 64, 256, 0, stream>>>(pre, stats + l * 256, gamma + l * DD,
                                               beta + l * DD, dinv, Wt_h + l * 16384,
                                               Wt_l + l * 16384, hwT_h, hwT_l);
        else
            k_bn_pool<<<NN / 64, 256, 0, stream>>>(pre, stats + l * 256, gamma + l * DD,
                                                   beta + l * DD, meansum);
    }
    k_tg<<<BG, 128, 0, stream>>>(meansum, Watt, tgbuf);
    k_coef_gf<<<NN / 64, 256, 0, stream>>>(pre, tgbuf, gf);
    k_out<<<NN * 64 / 256, 256, 0, stream>>>(pre, gf, out);
}

// Round 9
// 520.856 us; speedup vs baseline: 1.8193x; 1.0346x over previous
//
#include <hip/hip_runtime.h>
#include <hip/hip_bf16.h>
#include <math.h>

#define NN 32768      // B*NPG nodes
#define BG 64         // graphs
#define NPGC 512      // nodes per graph
#define DD 128        // hidden dim
#define EE 524288     // edges
#define LL 10         // layers
#define EPSF 1e-5f
#define PADK 72       // LDS row pitch (halfwords): 144B rows -> 2-way conflicts only (free, m136)

typedef __attribute__((ext_vector_type(8))) short short8;
typedef __attribute__((ext_vector_type(4))) float float4v;

static __device__ __forceinline__ unsigned short f2bf(float x) {
    __hip_bfloat16 b = __float2bfloat16(x);
    return *reinterpret_cast<unsigned short*>(&b);
}
static __device__ __forceinline__ float bf2f(unsigned short u) {
    unsigned int v = ((unsigned int)u) << 16;
    return __uint_as_float(v);
}
// split x into hi+lo bf16 (residual <= 2^-18 |x|)
static __device__ __forceinline__ void splitbf(float x, unsigned short& h, unsigned short& l) {
    unsigned short hh = f2bf(x);
    h = hh;
    l = f2bf(x - bf2f(hh));
}

// XCD swizzle (confirmed R4): graph g work on blocks with blockIdx%8 == g%8.
// Aggregation: Adj = diag(dinv) M diag(dinv), M = A+I integer -> exact bf16
// A-operand -> 2 MFMA passes. M built as packed-ushort histogram (2 cells/int).

// ---------------- prologue ----------------
__global__ void k_histM(const int* __restrict__ src, const int* __restrict__ dst,
                        unsigned int* __restrict__ Mp, int* __restrict__ cnt) {
    int e = blockIdx.x * 256 + threadIdx.x;
    int d = dst[e], s = src[e] & 511;
    int cell = (d << 9) + s;
    atomicAdd(&Mp[cell >> 1], 1u << ((cell & 1) << 4));
    atomicAdd(&cnt[d], 1);
}

__global__ void k_dinv(const int* __restrict__ cnt, float* __restrict__ dinv) {
    int n = blockIdx.x * 256 + threadIdx.x;
    dinv[n] = rsqrtf(1.0f + (float)cnt[n]);
}

// packed counters -> bf16 M rows with +1 on the (local) diagonal. 8 cells/thread.
__global__ void k_conv(const unsigned int* __restrict__ Mp, unsigned short* __restrict__ Mh) {
    int idx = (blockIdx.x * 256 + threadIdx.x) * 8;   // cell base
    uint4 v = *(const uint4*)(Mp + (idx >> 1));
    unsigned int c[8] = {v.x & 0xffffu, v.x >> 16, v.y & 0xffffu, v.y >> 16,
                         v.z & 0xffffu, v.z >> 16, v.w & 0xffffu, v.w >> 16};
    int diag = (idx >> 9) & 511;     // local diagonal column of this row
    int cb = idx & 511;
    unsigned short us[8];
    #pragma unroll
    for (int j = 0; j < 8; j++)
        us[j] = f2bf((float)(c[j] + ((cb + j == diag) ? 1u : 0u)));
    *(uint4*)(Mh + idx) = *(uint4*)us;
}

// Wt[l][f'][f] = split(W_rest[l][f][f'])
__global__ void k_wt(const float* __restrict__ Wr, unsigned short* __restrict__ Wt_h,
                     unsigned short* __restrict__ Wt_l) {
    int idx = blockIdx.x * 256 + threadIdx.x;   // over 9*16384
    int l = idx >> 14, rem = idx & 16383;
    int fp = rem >> 7, f = rem & 127;
    unsigned short h, lo;
    splitbf(Wr[l * 16384 + f * 128 + fp], h, lo);
    Wt_h[idx] = h;
    Wt_l[idx] = lo;
}

// layer-0: hwT[f][n] = split(dinv[n] * x[n] * W0[f])
__global__ void k_l0(const float* __restrict__ x, const float* __restrict__ W0,
                     const float* __restrict__ dinv,
                     unsigned short* __restrict__ hwT_h, unsigned short* __restrict__ hwT_l) {
    int u = blockIdx.x * 256 + threadIdx.x;     // 128*4096 units of 8 nodes
    int f = u >> 12, n0 = (u & 4095) * 8;
    float w = W0[f];
    float4 xa = *(const float4*)(x + n0);
    float4 xb = *(const float4*)(x + n0 + 4);
    float4 da = *(const float4*)(dinv + n0);
    float4 db = *(const float4*)(dinv + n0 + 4);
    float v[8] = {xa.x * w * da.x, xa.y * w * da.y, xa.z * w * da.z, xa.w * w * da.w,
                  xb.x * w * db.x, xb.y * w * db.y, xb.z * w * db.z, xb.w * w * db.w};
    unsigned short uh[8], ul[8];
    #pragma unroll
    for (int i = 0; i < 8; i++) splitbf(v[i], uh[i], ul[i]);
    *(uint4*)(hwT_h + (size_t)f * NN + n0) = *(uint4*)uh;
    *(uint4*)(hwT_l + (size_t)f * NN + n0) = *(uint4*)ul;
}

// ---------------- aggregation: pre = diag(dinv) (M @ hwT^T) + bias ---------
// 256 blocks (4/graph, XCD-swizzled): 128 dst x 128 feat, K=512, BK=64.
// Wave = 128 dst x 32 feat; a-frags cached in regs (a[8]) and reused across
// both B planes and both nt -> per-ks 12 ds_read_b128 vs 32 MFMA (MFMA-bound).
__global__ __launch_bounds__(256) void k_aggmm(const unsigned short* __restrict__ Mh,
        const unsigned short* __restrict__ hwT_h, const unsigned short* __restrict__ hwT_l,
        const float* __restrict__ dinv, const float* __restrict__ bias,
        float* __restrict__ pre, float* __restrict__ stats) {
    __shared__ unsigned short As[128 * PADK];                      // 18.4KB
    __shared__ unsigned short Bs_h[128 * PADK], Bs_l[128 * PADK];  // 36.9KB
    int t = threadIdx.x, lane = t & 63, wv = t >> 6;
    int l15 = lane & 15, quad = lane >> 4;
    int b = blockIdx.x, r = b & 7, q = b >> 3;   // q: 0..31
    int g = r + 8 * (q & 7);
    int mb = (q >> 3) * 128;                     // 4 chunks of 128 dst
    size_t arow = ((size_t)g * 512 + mb) * 512;
    size_t gcol = (size_t)g * 512;
    float4v acc[16];         // [mt 0..7][nt 0..1]
    #pragma unroll
    for (int i = 0; i < 16; i++) acc[i] = (float4v)0.f;

    for (int kc = 0; kc < 512; kc += 64) {
        __syncthreads();
        #pragma unroll
        for (int i = 0; i < 4; i++) {            // A: 128x64 = 1024 16B-units
            int u = t + i * 256;
            int row = u >> 3, ko = (u & 7) * 8;
            *(uint4*)(&As[row * PADK + ko]) =
                *(const uint4*)(Mh + arow + (size_t)row * 512 + kc + ko);
        }
        #pragma unroll
        for (int i = 0; i < 4; i++) {            // B planes: 1024 units each
            int u = t + i * 256;
            int f = u >> 3, ko = (u & 7) * 8;
            size_t go = (size_t)f * NN + gcol + kc + ko;
            *(uint4*)(&Bs_h[f * PADK + ko]) = *(const uint4*)(hwT_h + go);
            *(uint4*)(&Bs_l[f * PADK + ko]) = *(const uint4*)(hwT_l + go);
        }
        __syncthreads();
        int f0 = wv * 32;
        #pragma unroll
        for (int ks = 0; ks < 2; ks++) {
            int kb = ks * 32 + quad * 8;
            short8 a[8];
            #pragma unroll
            for (int mt = 0; mt < 8; mt++)
                a[mt] = *(const short8*)(&As[(mt * 16 + l15) * PADK + kb]);
            #pragma unroll
            for (int nt = 0; nt < 2; nt++) {
                short8 bh = *(const short8*)(&Bs_h[(f0 + nt * 16 + l15) * PADK + kb]);
                short8 bl = *(const short8*)(&Bs_l[(f0 + nt * 16 + l15) * PADK + kb]);
                #pragma unroll
                for (int mt = 0; mt < 8; mt++) {
                    acc[mt * 2 + nt] = __builtin_amdgcn_mfma_f32_16x16x32_bf16(a[mt], bh, acc[mt * 2 + nt], 0, 0, 0);
                    acc[mt * 2 + nt] = __builtin_amdgcn_mfma_f32_16x16x32_bf16(a[mt], bl, acc[mt * 2 + nt], 0, 0, 0);
                }
            }
        }
    }
    // epilogue: C/D col=l15 -> feat, row=quad*4+rg -> dst-local (verified R7/R8)
    int gbase = g * 512 + mb;
    int fA = wv * 32 + l15;
    float bf0 = bias[fA], bf1 = bias[fA + 16];
    float cs[2] = {0.f, 0.f}, cq[2] = {0.f, 0.f};
    #pragma unroll
    for (int mt = 0; mt < 8; mt++) {
        int n0 = gbase + mt * 16 + quad * 4;
        float4 dv = *(const float4*)(dinv + n0);
        #pragma unroll
        for (int nt = 0; nt < 2; nt++) {
            int f = fA + nt * 16;
            float bf = nt ? bf1 : bf0;
            float4v a = acc[mt * 2 + nt];
            float v0 = fmaf(dv.x, a[0], bf);
            float v1 = fmaf(dv.y, a[1], bf);
            float v2 = fmaf(dv.z, a[2], bf);
            float v3 = fmaf(dv.w, a[3], bf);
            pre[(size_t)(n0 + 0) * 128 + f] = v0;
            pre[(size_t)(n0 + 1) * 128 + f] = v1;
            pre[(size_t)(n0 + 2) * 128 + f] = v2;
            pre[(size_t)(n0 + 3) * 128 + f] = v3;
            cs[nt] += v0 + v1 + v2 + v3;
            cq[nt] = fmaf(v0, v0, cq[nt]); cq[nt] = fmaf(v1, v1, cq[nt]);
            cq[nt] = fmaf(v2, v2, cq[nt]); cq[nt] = fmaf(v3, v3, cq[nt]);
        }
    }
    #pragma unroll
    for (int nt = 0; nt < 2; nt++) {
        float cs_ = cs[nt], cq_ = cq[nt];
        cs_ += __shfl_xor(cs_, 16); cs_ += __shfl_xor(cs_, 32);
        cq_ += __shfl_xor(cq_, 16); cq_ += __shfl_xor(cq_, 32);
        if (quad == 0) {
            atomicAdd(&stats[fA + nt * 16], cs_);
            atomicAdd(&stats[128 + fA + nt * 16], cq_);
        }
    }
}

// ---------------- feature matmul: hwT_next = dinv ⊙ (relu(bn(pre)) @ W)^T --
// C = Wt @ X^T, M=128 f', N=64 nodes, K=128, split-precision 3-pass.
__global__ __launch_bounds__(256) void k_mmT(const float* __restrict__ pre,
        const float* __restrict__ stats, const float* __restrict__ gamma,
        const float* __restrict__ beta, const float* __restrict__ dinv,
        const unsigned short* __restrict__ Wt_h, const unsigned short* __restrict__ Wt_l,
        unsigned short* __restrict__ hwT_h, unsigned short* __restrict__ hwT_l) {
    __shared__ unsigned short Ws_h[128 * PADK], Ws_l[128 * PADK];  // 36.9KB
    __shared__ unsigned short Xs_h[64 * PADK], Xs_l[64 * PADK];    // 18.4KB
    __shared__ float scL[256];
    int t = threadIdx.x, lane = t & 63, wv = t >> 6;
    int l15 = lane & 15, quad = lane >> 4;
    int b = blockIdx.x, r = b & 7, q = b >> 3;
    int g = r + 8 * (q & 7);
    int nb = g * NPGC + (q >> 3) * 64;
    if (t < 128) {
        float mu = stats[t] * (1.0f / NN);
        float var = stats[128 + t] * (1.0f / NN) - mu * mu;
        float s = gamma[t] * rsqrtf(var + EPSF);
        scL[t] = s;
        scL[128 + t] = fmaf(-mu, s, beta[t]);
    }
    float4v acc[8];
    #pragma unroll
    for (int i = 0; i < 8; i++) acc[i] = (float4v)0.f;

    for (int kc = 0; kc < 128; kc += 64) {
        __syncthreads();    // first iter: publishes scL
        #pragma unroll
        for (int i = 0; i < 4; i++) {            // Wt planes: 1024 units each
            int u = t + i * 256;
            int fp = u >> 3, ko = (u & 7) * 8;
            int go = fp * 128 + kc + ko;
            *(uint4*)(&Ws_h[fp * PADK + ko]) = *(const uint4*)(Wt_h + go);
            *(uint4*)(&Ws_l[fp * PADK + ko]) = *(const uint4*)(Wt_l + go);
        }
        #pragma unroll
        for (int i = 0; i < 2; i++) {            // X: 512 units, bn+relu+split
            int u = t + i * 256;
            int n = u >> 3, fo = (u & 7) * 8;
            const float* pp = pre + (size_t)(nb + n) * 128 + kc + fo;
            float4 v0 = *(const float4*)(pp);
            float4 v1 = *(const float4*)(pp + 4);
            float4 s0 = *(const float4*)(&scL[kc + fo]);
            float4 s1 = *(const float4*)(&scL[kc + fo + 4]);
            float4 h0 = *(const float4*)(&scL[128 + kc + fo]);
            float4 h1 = *(const float4*)(&scL[128 + kc + fo + 4]);
            float v[8] = {fmaxf(fmaf(v0.x, s0.x, h0.x), 0.f),
                          fmaxf(fmaf(v0.y, s0.y, h0.y), 0.f),
                          fmaxf(fmaf(v0.z, s0.z, h0.z), 0.f),
                          fmaxf(fmaf(v0.w, s0.w, h0.w), 0.f),
                          fmaxf(fmaf(v1.x, s1.x, h1.x), 0.f),
                          fmaxf(fmaf(v1.y, s1.y, h1.y), 0.f),
                          fmaxf(fmaf(v1.z, s1.z, h1.z), 0.f),
                          fmaxf(fmaf(v1.w, s1.w, h1.w), 0.f)};
            unsigned short uh[8], ul[8];
            #pragma unroll
            for (int j = 0; j < 8; j++) splitbf(v[j], uh[j], ul[j]);
            *(uint4*)(&Xs_h[n * PADK + fo]) = *(uint4*)uh;
            *(uint4*)(&Xs_l[n * PADK + fo]) = *(uint4*)ul;
        }
        __syncthreads();
        int m0 = wv * 32;
        #pragma unroll
        for (int ks = 0; ks < 2; ks++) {
            int kb = ks * 32 + quad * 8;
            short8 a0h = *(const short8*)(&Ws_h[(m0 + l15) * PADK + kb]);
            short8 a0l = *(const short8*)(&Ws_l[(m0 + l15) * PADK + kb]);
            short8 a1h = *(const short8*)(&Ws_h[(m0 + 16 + l15) * PADK + kb]);
            short8 a1l = *(const short8*)(&Ws_l[(m0 + 16 + l15) * PADK + kb]);
            #pragma unroll
            for (int nt = 0; nt < 4; nt++) {
                short8 bh = *(const short8*)(&Xs_h[(nt * 16 + l15) * PADK + kb]);
                short8 bl = *(const short8*)(&Xs_l[(nt * 16 + l15) * PADK + kb]);
                acc[nt]     = __builtin_amdgcn_mfma_f32_16x16x32_bf16(a0h, bh, acc[nt], 0, 0, 0);
                acc[nt]     = __builtin_amdgcn_mfma_f32_16x16x32_bf16(a0h, bl, acc[nt], 0, 0, 0);
                acc[nt]     = __builtin_amdgcn_mfma_f32_16x16x32_bf16(a0l, bh, acc[nt], 0, 0, 0);
                acc[4 + nt] = __builtin_amdgcn_mfma_f32_16x16x32_bf16(a1h, bh, acc[4 + nt], 0, 0, 0);
                acc[4 + nt] = __builtin_amdgcn_mfma_f32_16x16x32_bf16(a1h, bl, acc[4 + nt], 0, 0, 0);
                acc[4 + nt] = __builtin_amdgcn_mfma_f32_16x16x32_bf16(a1l, bh, acc[4 + nt], 0, 0, 0);
            }
        }
    }
    #pragma unroll
    for (int mt = 0; mt < 2; mt++) {
        #pragma unroll
        for (int nt = 0; nt < 4; nt++) {
            int n = nb + nt * 16 + l15;
            float dv = dinv[n];
            int fp0 = wv * 32 + mt * 16 + quad * 4;
            float4v a = acc[mt * 4 + nt];
            #pragma unroll
            for (int rg = 0; rg < 4; rg++) {
                unsigned short h, lo;
                splitbf(dv * a[rg], h, lo);
                hwT_h[(size_t)(fp0 + rg) * NN + n] = h;
                hwT_l[(size_t)(fp0 + rg) * NN + n] = lo;
            }
        }
    }
}

// last layer: BN+ReLU in-place + per-graph column sums. 512 blocks, swizzled.
__global__ __launch_bounds__(256) void k_bn_pool(float* __restrict__ pre,
        const float* __restrict__ stats, const float* __restrict__ gamma,
        const float* __restrict__ beta, float* __restrict__ meansum) {
    __shared__ float ssum[256];
    __shared__ float scL[256];
    int t = threadIdx.x;
    int b = blockIdx.x, r = b & 7, q = b >> 3;
    int g = r + 8 * (q & 7);
    int nb = g * NPGC + (q >> 3) * 64;
    if (t < 128) {
        float mu = stats[t] * (1.0f / NN);
        float var = stats[128 + t] * (1.0f / NN) - mu * mu;
        float s = gamma[t] * rsqrtf(var + EPSF);
        scL[t] = s;
        scL[128 + t] = fmaf(-mu, s, beta[t]);
    }
    __syncthreads();
    int f = t & 127;
    float s = scL[f], sh = scL[128 + f];
    float lsum = 0.f;
    int base = nb * 128;
    for (int i = 0; i < 32; i++) {
        int idx = base + i * 256 + t;
        float v = fmaxf(fmaf(pre[idx], s, sh), 0.f);
        pre[idx] = v;
        lsum += v;
    }
    ssum[t] = lsum;
    __syncthreads();
    if (t < 128) atomicAdd(&meansum[g * 128 + f], ssum[t] + ssum[t + 128]);
}

// tg = tanh((meansum/512) @ W_att), per graph
__global__ void k_tg(const float* __restrict__ meansum, const float* __restrict__ Watt,
                     float* __restrict__ tg) {
    __shared__ float m[128];
    int g = blockIdx.x, t = threadIdx.x;  // 128 threads
    m[t] = meansum[g * 128 + t] * (1.0f / NPGC);
    __syncthreads();
    float a2 = 0.f;
    for (int k = 0; k < 128; k++) a2 = fmaf(m[k], Watt[k * 128 + t], a2);
    tg[g * 128 + t] = tanhf(a2);
}

// coefs = sigmoid(10*<h,tg>) and gf += coef*h. 512 blocks, swizzled.
__global__ __launch_bounds__(256) void k_coef_gf(const float* __restrict__ h,
        const float* __restrict__ tg, float* __restrict__ gf) {
    __shared__ float tgs[128];
    __shared__ float coef[64];
    int t = threadIdx.x;
    int b = blockIdx.x, r = b & 7, q = b >> 3;
    int g = r + 8 * (q & 7);
    int n0 = (q >> 3) * 64;
    if (t < 128) tgs[t] = tg[g * 128 + t];
    __syncthreads();
    int wid = t >> 6, lane = t & 63;
    const float* hp = h + (size_t)g * NPGC * 128;
    for (int j = wid; j < 64; j += 4) {
        int n = n0 + j;
        float p = hp[n * 128 + lane] * tgs[lane] + hp[n * 128 + 64 + lane] * tgs[64 + lane];
        for (int off = 32; off; off >>= 1) p += __shfl_xor(p, off);
        if (lane == 0) coef[j] = 1.0f / (1.0f + expf(-10.0f * p));
    }
    __syncthreads();
    int f = t & 127, half = t >> 7;
    float acc = 0.f;
    for (int j = 0; j < 32; j++) {
        int jj = half * 32 + j;
        acc = fmaf(coef[jj], hp[(n0 + jj) * 128 + f], acc);
    }
    atomicAdd(&gf[g * 128 + f], acc);
}

// output writer
__global__ void k_out(const float* __restrict__ h, const float* __restrict__ gf,
                      float* __restrict__ out) {
    int idx = blockIdx.x * 256 + threadIdx.x;
    int c4 = (idx & 63) * 4;
    int n = idx >> 6;
    int g = n >> 9;
    float4 v = (c4 < 128) ? *(const float4*)(h + (size_t)n * 128 + c4)
                          : *(const float4*)(gf + g * 128 + (c4 - 128));
    *(float4*)(out + (size_t)idx * 4) = v;
}

// ---------------- host ----------------
extern "C" void kernel_launch(void* const* d_in, const int* in_sizes, int n_in,
                              void* d_out, int out_size, void* d_ws, size_t ws_size,
                              hipStream_t stream) {
    const float* x     = (const float*)d_in[0];
    const int*   esrc  = (const int*)d_in[1];
    const int*   edst  = (const int*)d_in[2];
    const float* W0    = (const float*)d_in[4];
    const float* b0    = (const float*)d_in[5];
    const float* Wr    = (const float*)d_in[6];
    const float* br    = (const float*)d_in[7];
    const float* gamma = (const float*)d_in[8];
    const float* beta  = (const float*)d_in[9];
    const float* Watt  = (const float*)d_in[10];
    float* out = (float*)d_out;
    float* ws  = (float*)d_ws;

    // workspace layout (float units), ~85MB
    int*   cnt     = (int*)(ws + 0);             // 32768
    float* dinv    = ws + 32768;                 // 32768
    float* stats   = ws + 65536;                 // 2560
    float* tgbuf   = ws + 68096;                 // 8192
    float* meansum = ws + 76288;                 // 8192
    float* gf      = ws + 84480;                 // 8192
    unsigned short* Wt_h  = (unsigned short*)(ws + 92672);     // 147456 sh
    unsigned short* Wt_l  = (unsigned short*)(ws + 166400);
    unsigned short* hwT_h = (unsigned short*)(ws + 240128);    // 4.19M sh
    unsigned short* hwT_l = (unsigned short*)(ws + 2337280);
    unsigned short* Mh    = (unsigned short*)(ws + 4434432);   // NN*512 sh
    unsigned int* Mp = (unsigned int*)(ws + 12823040);   // NN*256 packed (dead after k_conv)
    float* pre     = ws + 12823040;              // aliases Mp; first write in k_aggmm
    // end: 21211648 floats = 84.8MB

    hipMemsetAsync(cnt, 0, NN * sizeof(int), stream);
    hipMemsetAsync(stats, 0, LL * 256 * sizeof(float), stream);
    hipMemsetAsync(meansum, 0, BG * 128 * sizeof(float), stream);
    hipMemsetAsync(gf, 0, BG * 128 * sizeof(float), stream);
    hipMemsetAsync(Mp, 0, (size_t)NN * 256 * sizeof(int), stream);

    k_histM<<<EE / 256, 256, 0, stream>>>(esrc, edst, Mp, cnt);
    k_dinv<<<NN / 256, 256, 0, stream>>>(cnt, dinv);
    k_conv<<<NN * 512 / 8 / 256, 256, 0, stream>>>(Mp, Mh);
    k_wt<<<9 * 16384 / 256, 256, 0, stream>>>(Wr, Wt_h, Wt_l);
    k_l0<<<128 * (NN / 8) / 256, 256, 0, stream>>>(x, W0, dinv, hwT_h, hwT_l);

    for (int l = 0; l < LL; l++) {
        const float* bias = (l == 0) ? b0 : br + (l - 1) * DD;
        k_aggmm<<<NN / 128, 256, 0, stream>>>(Mh, hwT_h, hwT_l, dinv, bias,
                                              pre, stats + l * 256);
        if (l < LL - 1)
            k_mmT<<<NN / 64, 256, 0, stream>>>(pre, stats + l * 256, gamma + l * DD,
                                               beta + l * DD, dinv, Wt_h + l * 16384,
                                               Wt_l + l * 16384, hwT_h, hwT_l);
        else
            k_bn_pool<<<NN / 64, 256, 0, stream>>>(pre, stats + l * 256, gamma + l * DD,
                                                   beta + l * DD, meansum);
    }
    k_tg<<<BG, 128, 0, stream>>>(meansum, Watt, tgbuf);
    k_coef_gf<<<NN / 64, 256, 0, stream>>>(pre, tgbuf, gf);
    k_out<<<NN * 64 / 256, 256, 0, stream>>>(pre, gf, out);
}